// Round 6
// baseline (236.206 us; speedup 1.0000x reference)
//
#include <hip/hip_runtime.h>
#include <hip/hip_bf16.h>

// B=2, L=1024, E=512, H=8, D=64, P=64
// inputs: seq [2,1024,512], pair [2,1024,1024,64], W_qkv [512,1536],
//         W_bias [64,8], W_out [512,512], b_out [512]   (all fp32)

typedef __attribute__((ext_vector_type(8))) short bf16x8;
typedef __attribute__((ext_vector_type(4))) float f32x4;

__device__ __forceinline__ unsigned pk2(float a, float b) {
    __hip_bfloat16 ha = __float2bfloat16(a);
    __hip_bfloat16 hb = __float2bfloat16(b);
    return (unsigned)__bfloat16_as_ushort(ha) | ((unsigned)__bfloat16_as_ushort(hb) << 16);
}

// nt (non-temporal) pair staging: keeps the zero-reuse 512 MB stream from
// evicting K/V out of L2/L3.
__device__ __forceinline__ void gl16_nt(const void* g, void* l) {
    __builtin_amdgcn_global_load_lds((const __attribute__((address_space(1))) void*)g,
                                     (__attribute__((address_space(3))) void*)l, 16, 0, 2);
}

// ---------------------------------------------------------------------------
// Kernel 1: QKV GEMM.  A[2048][512] @ W[512][1536] ->
//   q  bf16 [B][H][L][D] scaled by 1/8
//   k  bf16 [B][H][L][D]
//   vT bf16 [B][H][D][L]
// ---------------------------------------------------------------------------
__global__ __launch_bounds__(256, 2) void gemm_qkv_kernel(
    const float* __restrict__ A, const float* __restrict__ W,
    unsigned short* __restrict__ qbus, unsigned short* __restrict__ kbus,
    unsigned short* __restrict__ vtbus)
{
    __shared__ float smem[64 * 68];
    float* As = smem;                        // As[k][m]
    float* Bs = smem + 32 * 68;              // Bs[k][n]

    const int t  = threadIdx.x;
    const int m0 = blockIdx.y * 64;
    const int n0 = blockIdx.x * 64;
    const int tx = t & 15, ty = t >> 4;

    const int am = t >> 2, ak = (t & 3) * 8;
    const int bk = t >> 3, bn = (t & 7) * 8;

    float acc[4][4] = {};

    for (int k0 = 0; k0 < 512; k0 += 32) {
        float4 a0 = *(const float4*)&A[(size_t)(m0 + am) * 512 + k0 + ak];
        float4 a1 = *(const float4*)&A[(size_t)(m0 + am) * 512 + k0 + ak + 4];
        float4 b0 = *(const float4*)&W[(size_t)(k0 + bk) * 1536 + n0 + bn];
        float4 b1 = *(const float4*)&W[(size_t)(k0 + bk) * 1536 + n0 + bn + 4];
        __syncthreads();
        As[(ak + 0) * 68 + am] = a0.x;
        As[(ak + 1) * 68 + am] = a0.y;
        As[(ak + 2) * 68 + am] = a0.z;
        As[(ak + 3) * 68 + am] = a0.w;
        As[(ak + 4) * 68 + am] = a1.x;
        As[(ak + 5) * 68 + am] = a1.y;
        As[(ak + 6) * 68 + am] = a1.z;
        As[(ak + 7) * 68 + am] = a1.w;
        *(float4*)&Bs[bk * 68 + bn]     = b0;
        *(float4*)&Bs[bk * 68 + bn + 4] = b1;
        __syncthreads();
#pragma unroll
        for (int kk = 0; kk < 32; kk++) {
            float4 a4 = *(float4*)&As[kk * 68 + ty * 4];
            float4 b4 = *(float4*)&Bs[kk * 68 + tx * 4];
            float av[4] = {a4.x, a4.y, a4.z, a4.w};
            float bv[4] = {b4.x, b4.y, b4.z, b4.w};
#pragma unroll
            for (int r = 0; r < 4; r++)
#pragma unroll
                for (int c = 0; c < 4; c++) acc[r][c] += av[r] * bv[c];
        }
    }

    const int sect = n0 >> 9;                // 0=q, 1=k, 2=v
    const int h    = (n0 >> 6) & 7;
    const int b    = m0 >> 10;
    const int i0   = m0 & 1023;

    if (sect == 2) {
        // transpose through LDS -> vT[b][h][d][j] (bf16)
        __syncthreads();
        float* T = smem;                     // [64][68]
#pragma unroll
        for (int r = 0; r < 4; r++)
#pragma unroll
            for (int c = 0; c < 4; c++)
                T[(tx * 4 + c) * 68 + (ty * 4 + r)] = acc[r][c];
        __syncthreads();
        const int dp = t >> 2, iq = (t & 3) * 16;
        unsigned short* dst = vtbus + (((size_t)(b * 8 + h)) * 64 + dp) * 1024 + i0 + iq;
#pragma unroll
        for (int u = 0; u < 4; u++) {
            float4 f = *(float4*)&T[dp * 68 + iq + u * 4];
            uint2 pkd; pkd.x = pk2(f.x, f.y); pkd.y = pk2(f.z, f.w);
            *(uint2*)&dst[u * 4] = pkd;
        }
    } else {
        unsigned short* dst = (sect == 0) ? qbus : kbus;
        const float sc = (sect == 0) ? 0.125f : 1.0f;   // 1/sqrt(64) folded into q
#pragma unroll
        for (int r = 0; r < 4; r++) {
            const int i = i0 + ty * 4 + r;
#pragma unroll
            for (int c = 0; c < 4; c += 2) {
                unsigned u = pk2(acc[r][c] * sc, acc[r][c + 1] * sc);
                *(unsigned*)&dst[(((size_t)(b * 8 + h)) * 1024 + i) * 64 + tx * 4 + c] = u;
            }
        }
    }
}

// ---------------------------------------------------------------------------
// slab fragment: 8 consecutive fp32 p-values of one slab row -> bf16x8 A-frag
// ---------------------------------------------------------------------------
__device__ __forceinline__ bf16x8 slab_frag(const char* rowb, int ks, int q4, int sw) {
    const int s0 = ks * 8 + q4 * 2;
    const float4 fa = *(const float4*)(rowb + (((s0    ) ^ sw) << 4));
    const float4 fb = *(const float4*)(rowb + (((s0 + 1) ^ sw) << 4));
    uint4 u;
    u.x = pk2(fa.x, fa.y); u.y = pk2(fa.z, fa.w);
    u.z = pk2(fb.x, fb.y); u.w = pk2(fb.z, fb.w);
    return *(bf16x8*)&u;
}

// ---------------------------------------------------------------------------
// Kernel 2: fused pair-bias flash attention (j-split + partial softmax).
// grid = 512 blocks = (b, i-tile of 8, j-half of 512) -> 2 blocks/CU,
// 512 threads = 8 waves (4 waves/SIMD total). Per j-tile of 16: slab
// [8ii][16j][64p] fp32 (32KB) double-buffered via global_load_lds (nt,
// pre-swizzled source). Bias via MFMA (wave w owns ii=2w,2w+1), QK/PV per
// head (wave=head) via MFMA. Output: un-normalized ctx partial + (m,l).
// ---------------------------------------------------------------------------
__global__ __launch_bounds__(512, 4) void attn_kernel(
    const float* __restrict__ pair, const float* __restrict__ Wb,
    const unsigned short* __restrict__ qbus, const unsigned short* __restrict__ kbus,
    const unsigned short* __restrict__ vtbus, float* __restrict__ cp,
    float* __restrict__ mlm, float* __restrict__ mll)
{
    __shared__ __align__(16) char plds[2][32768];            // slab: [128 rows][16 slots]
    __shared__ __align__(16) float bias_lds[128 * 17];       // [row=ii*16+j][h pad 17]
    __shared__ __align__(16) unsigned short pbuf[8 * 16 * 24]; // [h][i16][j pad 24]

    const int t    = threadIdx.x;
    const int lane = t & 63;
    const int w    = t >> 6;            // wave id == head (QK/PV); owns ii=2w,2w+1 (bias)
    const int q4   = lane >> 4;
    const int l15  = lane & 15;

    // XCD-aware mapping: 64 contiguous vbids per XCD -> one (b, j-half) per
    // XCD -> K/V working set 1 MB, L2-resident.
    const int bx   = blockIdx.x;
    const int vbid = ((bx & 7) << 6) | (bx >> 3);
    const int b    = vbid >> 8;
    const int rem  = vbid & 255;
    const int jh   = rem >> 7;                // j-half: 0 or 1
    const int i0   = (rem & 127) * 8;

    // W_bias B-fragments (2 k-steps), col h = l15 (zero-pad h>=8)
    uint4 wbf[2];
#pragma unroll
    for (int ks = 0; ks < 2; ks++) {
        float f[8];
#pragma unroll
        for (int e = 0; e < 8; e++)
            f[e] = (l15 < 8) ? Wb[(ks * 32 + q4 * 8 + e) * 8 + l15] : 0.f;
        wbf[ks].x = pk2(f[0], f[1]); wbf[ks].y = pk2(f[2], f[3]);
        wbf[ks].z = pk2(f[4], f[5]); wbf[ks].w = pk2(f[6], f[7]);
    }

    // Q A-fragments (2 k-steps): row i = i0 + l15 (pad rows 8-15 = 0)
    uint4 qf[2] = {};
    if (l15 < 8) {
        const unsigned short* qrow = qbus + (size_t)((b * 8 + w) * 1024 + i0 + l15) * 64;
#pragma unroll
        for (int ks = 0; ks < 2; ks++)
            qf[ks] = *(const uint4*)(qrow + ks * 32 + q4 * 8);
    }

    // staging: round r=0..3, slab row r_s = r*32 + w*4 + q4 (ii=r_s>>4, j=r_s&15),
    // LDS dest = w*1024 + r*8192 + lane*16 (linear), global slot = l15 ^ (r_s&15).
    const int rb = w * 4 + q4;
    const char* pairB = (const char*)pair + (size_t)(b * 1024 + i0) * 262144
                      + (size_t)jh * 131072
                      + (rb >> 4) * 262144 + (rb & 15) * 256 + ((l15 ^ (rb & 15)) << 4);
    char* ldsW = (char*)plds + w * 1024;

#define STAGE(bufsel, jtn) do {                                         \
        const char* gg = pairB + (size_t)(jtn) * 4096;                  \
        char* ld = ldsW + (bufsel) * 32768;                             \
        _Pragma("unroll")                                               \
        for (int r = 0; r < 4; r++)                                     \
            gl16_nt(gg + (size_t)r * 524288, ld + r * 8192);            \
    } while (0)

    STAGE(0, 0);

    f32x4 acc[4];
#pragma unroll
    for (int dn = 0; dn < 4; dn++) acc[dn] = (f32x4){0.f, 0.f, 0.f, 0.f};
    float mrun[4], lrun[4];
#pragma unroll
    for (int rr = 0; rr < 4; rr++) { mrun[rr] = -3.0e38f; lrun[rr] = 0.f; }

    const unsigned short* kbase = kbus + (size_t)((b * 8 + w) * 1024 + jh * 512) * 64;
    const unsigned short* vbase = vtbus + (size_t)((b * 8 + w) * 64) * 1024 + jh * 512;

    for (int jt = 0; jt < 32; jt++) {
        // ---- wait own stage complete, all waves ready ----
        asm volatile("s_waitcnt vmcnt(0) lgkmcnt(0)" ::: "memory");
        __builtin_amdgcn_sched_barrier(0);
        __builtin_amdgcn_s_barrier();
        __builtin_amdgcn_sched_barrier(0);

        const char* cur = (const char*)plds + (jt & 1) * 32768;

        // ---- K/V fragment loads (L2-resident) ----
        uint4 kf[2], vf[4];
        {
            const unsigned short* kt = kbase + (size_t)(jt * 16 + l15) * 64;
#pragma unroll
            for (int ks = 0; ks < 2; ks++)
                kf[ks] = *(const uint4*)(kt + ks * 32 + q4 * 8);
#pragma unroll
            for (int dn = 0; dn < 4; dn++)
                vf[dn] = *(const uint4*)(vbase + (size_t)(dn * 16 + l15) * 1024
                                         + jt * 16 + (q4 & 1) * 8);
        }

        // ---- issue async stage of next slab ----
        if (jt < 31) STAGE((jt + 1) & 1, jt + 1);

        // ---- bias via MFMA: wave w owns slab rows 32w..32w+31 ----
        {
            const char* rb0 = cur + (32 * w + l15) * 256;        // g=0
            const char* rb1 = cur + (32 * w + 16 + l15) * 256;   // g=1
            f32x4 b0 = {0.f, 0.f, 0.f, 0.f}, b1 = {0.f, 0.f, 0.f, 0.f};
#pragma unroll
            for (int ks = 0; ks < 2; ks++) {
                bf16x8 a0 = slab_frag(rb0, ks, q4, l15);
                b0 = __builtin_amdgcn_mfma_f32_16x16x32_bf16(a0, *(bf16x8*)&wbf[ks], b0, 0, 0, 0);
                bf16x8 a1 = slab_frag(rb1, ks, q4, l15);
                b1 = __builtin_amdgcn_mfma_f32_16x16x32_bf16(a1, *(bf16x8*)&wbf[ks], b1, 0, 0, 0);
            }
            if (l15 < 8) {
#pragma unroll
                for (int rr = 0; rr < 4; rr++) {
                    bias_lds[(32 * w + q4 * 4 + rr) * 17 + l15]      = b0[rr];
                    bias_lds[(32 * w + 16 + q4 * 4 + rr) * 17 + l15] = b1[rr];
                }
            }
        }

        // ---- bias visible to all waves ----
        asm volatile("s_waitcnt lgkmcnt(0)" ::: "memory");
        __builtin_amdgcn_sched_barrier(0);
        __builtin_amdgcn_s_barrier();
        __builtin_amdgcn_sched_barrier(0);

        // ---- QK via MFMA, C-init = bias (rows i = q4*4+rr, valid q4<2) ----
        f32x4 s;
#pragma unroll
        for (int rr = 0; rr < 4; rr++)
            s[rr] = (q4 < 2) ? bias_lds[((q4 * 4 + rr) * 16 + l15) * 17 + w] : 0.f;
        s = __builtin_amdgcn_mfma_f32_16x16x32_bf16(*(bf16x8*)&qf[0], *(bf16x8*)&kf[0], s, 0, 0, 0);
        s = __builtin_amdgcn_mfma_f32_16x16x32_bf16(*(bf16x8*)&qf[1], *(bf16x8*)&kf[1], s, 0, 0, 0);

        // ---- online softmax (16-lane row groups) ----
#pragma unroll
        for (int rr = 0; rr < 4; rr++) {
            float x = s[rr];
            x = fmaxf(x, __shfl_xor(x, 1));
            x = fmaxf(x, __shfl_xor(x, 2));
            x = fmaxf(x, __shfl_xor(x, 4));
            x = fmaxf(x, __shfl_xor(x, 8));
            const float mnew = fmaxf(mrun[rr], x);
            const float corr = __expf(mrun[rr] - mnew);
            mrun[rr] = mnew;
            const float p0 = __expf(s[rr] - mnew);
            float ts = p0;
            ts += __shfl_xor(ts, 1);
            ts += __shfl_xor(ts, 2);
            ts += __shfl_xor(ts, 4);
            ts += __shfl_xor(ts, 8);
            lrun[rr] = lrun[rr] * corr + ts;
#pragma unroll
            for (int dn = 0; dn < 4; dn++) acc[dn][rr] *= corr;
            pbuf[(w * 16 + q4 * 4 + rr) * 24 + l15] =
                __bfloat16_as_ushort(__float2bfloat16(p0));
        }

        // ---- P writes -> A-frag read (same wave, cross-lane) ----
        asm volatile("s_waitcnt lgkmcnt(0)" ::: "memory");
        __builtin_amdgcn_sched_barrier(0);

        // PV: A rows = P rows (i=l15), k = j (16 valid, upper 16 zero)
        bf16x8 pfrag = (bf16x8){0, 0, 0, 0, 0, 0, 0, 0};
        if (q4 < 2) pfrag = *(bf16x8*)&pbuf[(w * 16 + l15) * 24 + q4 * 8];
#pragma unroll
        for (int dn = 0; dn < 4; dn++)
            acc[dn] = __builtin_amdgcn_mfma_f32_16x16x32_bf16(pfrag, *(bf16x8*)&vf[dn], acc[dn], 0, 0, 0);
    }

    // ---- epilogue: un-normalized partial + (m,l) ----
    if (q4 < 2) {
#pragma unroll
        for (int rr = 0; rr < 4; rr++) {
            const int i = q4 * 4 + rr;
            float* crow = cp + (size_t)jh * (2048 * 512)
                        + ((size_t)(b * 1024) + i0 + i) * 512 + w * 64;
#pragma unroll
            for (int dn = 0; dn < 4; dn++)
                crow[dn * 16 + l15] = acc[dn][rr];
            if (l15 == 0) {
                const int mi = ((jh * 2 + b) * 8 + w) * 1024 + i0 + i;
                mlm[mi] = mrun[rr];
                mll[mi] = lrun[rr];
            }
        }
    }
#undef STAGE
}

// ---------------------------------------------------------------------------
// Kernel 2b: merge the two j-half partials.
// out = (c0*e^{m0-M} + c1*e^{m1-M}) / (l0*e^{m0-M} + l1*e^{m1-M})
// ---------------------------------------------------------------------------
__global__ __launch_bounds__(256) void merge_kernel(
    const float* __restrict__ cp, const float* __restrict__ mlm,
    const float* __restrict__ mll, float* __restrict__ ctx)
{
    const int row = blockIdx.x;              // b*1024 + i
    const int b   = row >> 10, i = row & 1023;
    const int t   = threadIdx.x;
    const int h   = t >> 5;                  // e0 = t*2 -> h = e0>>6

    const int mi0 = ((0 * 2 + b) * 8 + h) * 1024 + i;
    const int mi1 = ((1 * 2 + b) * 8 + h) * 1024 + i;
    const float m0 = mlm[mi0], m1 = mlm[mi1];
    const float l0 = mll[mi0], l1 = mll[mi1];
    const float M  = fmaxf(m0, m1);
    const float w0 = __expf(m0 - M), w1 = __expf(m1 - M);
    const float inv = 1.0f / (l0 * w0 + l1 * w1);

    const float2 c0 = *(const float2*)&cp[(size_t)row * 512 + t * 2];
    const float2 c1 = *(const float2*)&cp[(size_t)(2048 * 512) + (size_t)row * 512 + t * 2];
    float2 o;
    o.x = (c0.x * w0 + c1.x * w1) * inv;
    o.y = (c0.y * w0 + c1.y * w1) * inv;
    *(float2*)&ctx[(size_t)row * 512 + t * 2] = o;
}

// ---------------------------------------------------------------------------
// Kernel 3: out = ctx[2048][512] @ W_out[512][512] + b_out
// ---------------------------------------------------------------------------
__global__ __launch_bounds__(256, 2) void gemm_out_kernel(
    const float* __restrict__ A, const float* __restrict__ W,
    const float* __restrict__ bias, float* __restrict__ out)
{
    __shared__ float smem[64 * 68];
    float* As = smem;
    float* Bs = smem + 32 * 68;

    const int t  = threadIdx.x;
    const int m0 = blockIdx.y * 64;
    const int n0 = blockIdx.x * 64;
    const int tx = t & 15, ty = t >> 4;

    const int am = t >> 2, ak = (t & 3) * 8;
    const int bk = t >> 3, bn = (t & 7) * 8;

    float acc[4][4] = {};

    for (int k0 = 0; k0 < 512; k0 += 32) {
        float4 a0 = *(const float4*)&A[(size_t)(m0 + am) * 512 + k0 + ak];
        float4 a1 = *(const float4*)&A[(size_t)(m0 + am) * 512 + k0 + ak + 4];
        float4 b0 = *(const float4*)&W[(size_t)(k0 + bk) * 512 + n0 + bn];
        float4 b1 = *(const float4*)&W[(size_t)(k0 + bk) * 512 + n0 + bn + 4];
        __syncthreads();
        As[(ak + 0) * 68 + am] = a0.x;
        As[(ak + 1) * 68 + am] = a0.y;
        As[(ak + 2) * 68 + am] = a0.z;
        As[(ak + 3) * 68 + am] = a0.w;
        As[(ak + 4) * 68 + am] = a1.x;
        As[(ak + 5) * 68 + am] = a1.y;
        As[(ak + 6) * 68 + am] = a1.z;
        As[(ak + 7) * 68 + am] = a1.w;
        *(float4*)&Bs[bk * 68 + bn]     = b0;
        *(float4*)&Bs[bk * 68 + bn + 4] = b1;
        __syncthreads();
#pragma unroll
        for (int kk = 0; kk < 32; kk++) {
            float4 a4 = *(float4*)&As[kk * 68 + ty * 4];
            float4 b4 = *(float4*)&Bs[kk * 68 + tx * 4];
            float av[4] = {a4.x, a4.y, a4.z, a4.w};
            float bv[4] = {b4.x, b4.y, b4.z, b4.w};
#pragma unroll
            for (int r = 0; r < 4; r++)
#pragma unroll
                for (int c = 0; c < 4; c++) acc[r][c] += av[r] * bv[c];
        }
    }

    float4 bo = *(const float4*)&bias[n0 + tx * 4];
    float bv[4] = {bo.x, bo.y, bo.z, bo.w};
#pragma unroll
    for (int r = 0; r < 4; r++) {
        const int m = m0 + ty * 4 + r;
#pragma unroll
        for (int c = 0; c < 4; c++)
            out[(size_t)m * 512 + n0 + tx * 4 + c] = acc[r][c] + bv[c];
    }
}

// ---------------------------------------------------------------------------
extern "C" void kernel_launch(void* const* d_in, const int* in_sizes, int n_in,
                              void* d_out, int out_size, void* d_ws, size_t ws_size,
                              hipStream_t stream)
{
    const float* seq  = (const float*)d_in[0];
    const float* pair = (const float*)d_in[1];
    const float* Wqkv = (const float*)d_in[2];
    const float* Wb   = (const float*)d_in[3];
    const float* Wout = (const float*)d_in[4];
    const float* bout = (const float*)d_in[5];
    float* out = (float*)d_out;

    unsigned short* qbus  = (unsigned short*)d_ws;           // bf16 [2][8][1024][64]  2 MB
    unsigned short* kbus  = qbus + (1 << 20);                // bf16 [2][8][1024][64]  2 MB
    unsigned short* vtbus = kbus + (1 << 20);                // bf16 [2][8][64][1024]  2 MB
    float*          ctx   = (float*)(vtbus + (1 << 20));     // fp32 [2][1024][512]    4 MB
    float*          cp    = ctx + (1 << 20);                 // fp32 [2][2048][512]    8 MB
    float*          mlm   = cp + (2 << 20);                  // fp32 [2][2][8][1024]   128 KB
    float*          mll   = mlm + (1 << 15);                 // fp32 [2][2][8][1024]   128 KB

    gemm_qkv_kernel<<<dim3(24, 32), 256, 0, stream>>>(seq, Wqkv, qbus, kbus, vtbus);
    attn_kernel<<<512, 512, 0, stream>>>(pair, Wb, qbus, kbus, vtbus, cp, mlm, mll);
    merge_kernel<<<2048, 256, 0, stream>>>(cp, mlm, mll, ctx);
    gemm_out_kernel<<<dim3(8, 32), 256, 0, stream>>>(ctx, Wout, bout, out);
}